// Round 10
// baseline (111.899 us; speedup 1.0000x reference)
//
#include <hip/hip_runtime.h>

// CurvatureLoss3D — R21: R20 kernel + grid, ONE change: __launch_bounds__
// (256, 8) to force VGPR <= 64.
// R20 post-mortem: VGPR crept 64->68, dropping the kernel from the
// 8-waves/SIMD tier to 4 (m69 halving model) -> 1368 blocks needed two
// dispatch rounds again; occupancy/VALUBusy unchanged (22%/52%). The
// occupancy experiment was invalidated by 4 registers, not refuted.
// Model now closes: VALU issue/phase/SIMD = 0.52*5400 = 2800 cy =
// ~680 cy/wave-phase x 2.8 resident waves -> issue-STARVED. Forcing the
// 8-wave tier: LDS 22KB caps 7 blocks/CU; 1368 = 5.34/CU in one round;
// resident waves/SIMD 2.8 -> 5.3.
// Risk: 4-reg deficit may spill (watch scratch/localMem; abort if so).
// Frozen: LDS staging (34x40 tiles), counted-vmcnt + raw s_barrier,
// two-kernel epilogue, pow2-folded arithmetic (bit-identical).

typedef float v2f __attribute__((ext_vector_type(2)));

constexpr int DIM  = 192;
constexpr int ODIM = 190;
constexpr int TX = 32, TY = 32, CZ = 10;
constexpr int NTX = 6, NTY = 6, NTZ = 19;     // 19*10 = 190 exactly
constexpr int PLANE = DIM * DIM;
constexpr int NBLOCKS = 2 * NTZ * NTY * NTX;  // 1368 = 5.34 blocks/CU

constexpr int LROW   = 40;                    // floats per LDS tile row
constexpr int LPLANE = 34 * LROW;             // 1360 floats = 5440 B/plane

struct Slice {
    v2f   q[3][4];          // rows y..y+2; q[dy][k] = (r[k], r[k+2])
    float xmn[4], xmx[4];   // per-voxel-window (3 rows x 3 cols) min/max, this plane
};

#define GLDS(srcp, dstp)                                                   \
    __builtin_amdgcn_global_load_lds(                                      \
        (const __attribute__((address_space(1))) void*)(srcp),             \
        (__attribute__((address_space(3))) void*)(dstp), 16, 0, 0)

#define WVM(n)  asm volatile("s_waitcnt vmcnt(" #n ")" ::: "memory")
#define BAR()   do { __builtin_amdgcn_s_barrier();                         \
                     asm volatile("" ::: "memory"); } while (0)

__global__ __launch_bounds__(256, 8) void curv_main(const float* __restrict__ phi,
                                                    double* __restrict__ acc,
                                                    int use_partials) {
    __shared__ float lds[4 * LPLANE];         // 21760 B

    int bx = blockIdx.x;
    const int tx = bx % NTX; bx /= NTX;
    const int ty = bx % NTY; bx /= NTY;
    const int tz = bx % NTZ; bx /= NTZ;
    const int n  = bx;

    const int xbase = tx * TX, ybase = ty * TY, zbase = tz * CZ;
    const int tid = threadIdx.x;
    const int row = tid >> 3;          // output y within tile (0..31)
    const int x0  = (tid & 7) * 4;     // output x within tile (0..28)
    const float* pn  = phi + (long long)n * DIM * PLANE;
    const float* pzb = pn + (long long)zbase * PLANE;   // zbase+g <= 180+11=191: ok

    // ---- staging map: 340 chunks = 34 rows x 10 float4-chunks ----
    const int lane = tid & 63, wave = tid >> 6;
    const int chA = tid;                         // chunks 0..255
    const int chB = 256 + wave * 21 + lane;      // chunks 256..339, 21/wave
    const bool bAct = lane < 21;                 // every wave: 2 vmem/STAGE (uniform)
    int rA = ybase + chA / 10;       if (rA > DIM - 1) rA = DIM - 1;
    int cA = xbase + (chA % 10) * 4; if (cA > DIM - 4) cA = DIM - 4;
    const int offA = rA * DIM + cA;
    int rB = ybase + chB / 10;       if (rB > DIM - 1) rB = DIM - 1;
    int cB = xbase + (chB % 10) * 4; if (cB > DIM - 4) cB = DIM - 4;
    const int offB = rB * DIM + cB;

#define STAGE(g, bi) do {                                                  \
    const float* b_ = pzb + (g) * PLANE;                                   \
    GLDS(b_ + offA, &lds[(bi) * LPLANE + chA * 4]);                        \
    if (bAct) GLDS(b_ + offB, &lds[(bi) * LPLANE + chB * 4]);              \
} while (0)

    // ---- consumer-side offsets (clamps already baked into LDS content) ----
    int lro[3];
#pragma unroll
    for (int dy = 0; dy < 3; ++dy) lro[dy] = (row + dy) * LROW;
    int c2r = x0 + 4;
    if (xbase + c2r > DIM - 2) c2r = DIM - 2 - xbase;   // last-tile col clamp

#define UNPACKL(S, bi) do {                                                \
    const float* lb_ = &lds[(bi) * LPLANE];                                \
    float mn6[6], mx6[6];                                                  \
    _Pragma("unroll")                                                      \
    for (int dy = 0; dy < 3; ++dy) {                                       \
        const float4 a = *(const float4*)(lb_ + lro[dy] + x0);             \
        const float2 b = *(const float2*)(lb_ + lro[dy] + c2r);            \
        (S).q[dy][0] = (v2f){a.x, a.z};                                    \
        (S).q[dy][1] = (v2f){a.y, a.w};                                    \
        (S).q[dy][2] = (v2f){a.z, b.x};                                    \
        (S).q[dy][3] = (v2f){a.w, b.y};                                    \
        if (dy == 0) {                                                     \
            mn6[0] = a.x; mn6[1] = a.y; mn6[2] = a.z;                      \
            mn6[3] = a.w; mn6[4] = b.x; mn6[5] = b.y;                      \
            mx6[0] = a.x; mx6[1] = a.y; mx6[2] = a.z;                      \
            mx6[3] = a.w; mx6[4] = b.x; mx6[5] = b.y;                      \
        } else {                                                           \
            mn6[0] = fminf(mn6[0], a.x); mx6[0] = fmaxf(mx6[0], a.x);      \
            mn6[1] = fminf(mn6[1], a.y); mx6[1] = fmaxf(mx6[1], a.y);      \
            mn6[2] = fminf(mn6[2], a.z); mx6[2] = fmaxf(mx6[2], a.z);      \
            mn6[3] = fminf(mn6[3], a.w); mx6[3] = fmaxf(mx6[3], a.w);      \
            mn6[4] = fminf(mn6[4], b.x); mx6[4] = fmaxf(mx6[4], b.x);      \
            mn6[5] = fminf(mn6[5], b.y); mx6[5] = fmaxf(mx6[5], b.y);      \
        }                                                                  \
    }                                                                      \
    _Pragma("unroll")                                                      \
    for (int j = 0; j < 4; ++j) {                                          \
        (S).xmn[j] = fminf(fminf(mn6[j], mn6[j + 1]), mn6[j + 2]);         \
        (S).xmx[j] = fmaxf(fmaxf(mx6[j], mx6[j + 1]), mx6[j + 2]);         \
    } } while (0)

    float fsp = 0.0f, fsc = 0.0f;
    const float EPSF = 1e-8f;
    const float EPS4 = 4e-8f;           // 4*eps (exact: eps scaled by 2^2)
    const int oy = ybase + row;

    bool vmask[4];
#pragma unroll
    for (int j = 0; j < 4; ++j)
        vmask[j] = (oy < ODIM) && (xbase + x0 + j < ODIM);

    auto compute = [&](const Slice& s0, const Slice& s1, const Slice& s2) {
        float wmn[4], wmx[4];
#pragma unroll
        for (int j = 0; j < 4; ++j) {
            wmn[j] = fminf(fminf(s0.xmn[j], s1.xmn[j]), s2.xmn[j]);
            wmx[j] = fmaxf(fmaxf(s0.xmx[j], s1.xmx[j]), s2.xmx[j]);
        }

#pragma unroll
        for (int p = 0; p < 2; ++p) {
            // raw differences: G = 2g, M = 4h_mixed (constants folded, exact)
            v2f Gx = s2.q[1][p + 1] - s0.q[1][p + 1];
            v2f Gy = s1.q[2][p + 1] - s1.q[0][p + 1];
            v2f Gz = s1.q[1][p + 2] - s1.q[1][p];

            v2f c2v = 2.0f * s1.q[1][p + 1];
            v2f hxx = s0.q[1][p + 1] - c2v + s2.q[1][p + 1];
            v2f hyy = s1.q[0][p + 1] - c2v + s1.q[2][p + 1];
            v2f hzz = s1.q[1][p] - c2v + s1.q[1][p + 2];

            v2f Mxy = s0.q[0][p + 1] - s0.q[2][p + 1]
                    - s2.q[0][p + 1] + s2.q[2][p + 1];
            v2f Mxz = s0.q[1][p] - s0.q[1][p + 2]
                    - s2.q[1][p] + s2.q[1][p + 2];
            v2f Myz = s1.q[0][p] - s1.q[0][p + 2]
                    - s1.q[2][p] + s1.q[2][p + 2];

            v2f Gx2 = Gx * Gx, Gy2 = Gy * Gy, Gz2 = Gz * Gz;
            v2f mag2G = Gx2 + Gy2 + Gz2 + EPS4;      // = 4*(mag2)

            v2f r = (v2f){ __builtin_amdgcn_rsqf(mag2G.x),
                           __builtin_amdgcn_rsqf(mag2G.y) };   // = inv1/2 exactly
            v2f r3 = r * r * r;                       // = inv3/8
            v2f twor3 = r3 + r3;                      // = inv3/4

            v2f crossG = Gx * Gy * Mxy + Gx * Gz * Mxz + Gy * Gz * Myz; // 16*cross

            v2f num1 = Gx2 * (hyy + hzz) + Gy2 * (hxx + hzz) +
                       Gz2 * (hxx + hyy) - 0.5f * crossG;      // 4*num_orig
            v2f mean_c = num1 * twor3;                // bit-exact vs original
            v2f lap   = (hxx + hyy + hzz) * (r + r);
            v2f num2  = Gx2 * hxx + Gy2 * hyy + Gz2 * hzz + 0.5f * crossG;
            v2f quad  = num2 * twor3;
            v2f gauss = lap - quad;

            v2f disc = mean_c * mean_c - gauss;
            v2f sq = (v2f){ sqrtf(fabsf(disc.x) + EPSF),
                            sqrtf(fabsf(disc.y) + EPSF) };
            v2f k1 = mean_c + sq;
            v2f t  = 2.0f * k1;                       // k1/(0.5+1e-8) == 2*k1
            v2f pen2 = t * t - 1.0f;

#pragma unroll
            for (int e = 0; e < 2; ++e) {
                const int j = p + 2 * e;
                float pen = fmaxf(e ? pen2.y : pen2.x, 0.0f);
                if (vmask[j] && (wmn[j] * wmx[j] < 0.0f)) {
                    fsp += pen;
                    fsc += 1.0f;
                }
            }
        }
    };

    Slice s0, s1, s2;

    // ---- prologue: planes 0..3 staged; 0,1 unpacked; pipeline primed ----
    STAGE(0, 0); STAGE(1, 1); STAGE(2, 2); STAGE(3, 3);   // 8 vmem/wave out
    WVM(6); BAR();               // plane 0 landed (all waves)
    UNPACKL(s0, 0);
    WVM(4); BAR();               // plane 1 landed; b0 free
    STAGE(4, 0);                 // out: {2,3,4} = 6
    UNPACKL(s1, 1);
    WVM(4); BAR();               // plane 2 landed; b1 free
    STAGE(5, 1);                 // out: {3,4,5} = 6
    // invariant at phase z: buf[(z+2)%4] ready; next 3 planes in flight.

    UNPACKL(s2, 2); compute(s0, s1, s2); WVM(4); BAR(); STAGE(6, 2);   // z=0
    UNPACKL(s0, 3); compute(s1, s2, s0); WVM(4); BAR(); STAGE(7, 3);   // z=1
    UNPACKL(s1, 0); compute(s2, s0, s1); WVM(4); BAR(); STAGE(8, 0);   // z=2
    UNPACKL(s2, 1); compute(s0, s1, s2); WVM(4); BAR(); STAGE(9, 1);   // z=3
    UNPACKL(s0, 2); compute(s1, s2, s0); WVM(4); BAR(); STAGE(10, 2);  // z=4
    UNPACKL(s1, 3); compute(s2, s0, s1); WVM(4); BAR(); STAGE(11, 3);  // z=5
    UNPACKL(s2, 0); compute(s0, s1, s2); WVM(4); BAR();                // z=6
    UNPACKL(s0, 1); compute(s1, s2, s0); WVM(2); BAR();                // z=7
    UNPACKL(s1, 2); compute(s2, s0, s1); WVM(0); BAR();                // z=8
    UNPACKL(s2, 3); compute(s0, s1, s2);                               // z=9

    // ---- reduction (double from here) ----
    double sp = (double)fsp, sc = (double)fsc;
#pragma unroll
    for (int off = 32; off > 0; off >>= 1) {
        sp += __shfl_down(sp, off, 64);
        sc += __shfl_down(sc, off, 64);
    }

    __shared__ double lsp[4], lsc[4];
    if (lane == 0) { lsp[wave] = sp; lsc[wave] = sc; }
    __syncthreads();
    if (tid == 0) {
        double tp = lsp[0] + lsp[1] + lsp[2] + lsp[3];
        double tc = lsc[0] + lsc[1] + lsc[2] + lsc[3];
        if (use_partials) {
            acc[2 * blockIdx.x]     = tp;
            acc[2 * blockIdx.x + 1] = tc;
        } else {
            atomicAdd(&acc[0], tp);
            atomicAdd(&acc[1], tc);
        }
    }
}

__global__ __launch_bounds__(256) void curv_reduce(const double* __restrict__ part,
                                                   int nblocks, int use_partials,
                                                   float* __restrict__ out) {
    double sp = 0.0, sc = 0.0;
    if (use_partials) {
        for (int i = threadIdx.x; i < nblocks; i += 256) {
            sp += part[2 * i];
            sc += part[2 * i + 1];
        }
    } else if (threadIdx.x == 0) {
        sp = part[0]; sc = part[1];
    }
#pragma unroll
    for (int off = 32; off > 0; off >>= 1) {
        sp += __shfl_down(sp, off, 64);
        sc += __shfl_down(sc, off, 64);
    }
    __shared__ double lsp[4], lsc[4];
    const int wave = threadIdx.x >> 6, lane = threadIdx.x & 63;
    if (lane == 0) { lsp[wave] = sp; lsc[wave] = sc; }
    __syncthreads();
    if (threadIdx.x == 0) {
        double tp = lsp[0] + lsp[1] + lsp[2] + lsp[3];
        double tc = lsc[0] + lsc[1] + lsc[2] + lsc[3];
        out[0] = (float)(tp / (tc + 1e-8));
    }
}

extern "C" void kernel_launch(void* const* d_in, const int* in_sizes, int n_in,
                              void* d_out, int out_size, void* d_ws, size_t ws_size,
                              hipStream_t stream) {
    const float* phi = (const float*)d_in[0];
    float* out = (float*)d_out;
    double* acc = (double*)d_ws;

    const int use_partials = (ws_size >= (size_t)(2 * NBLOCKS) * sizeof(double)) ? 1 : 0;
    if (!use_partials) {
        hipMemsetAsync(d_ws, 0, 2 * sizeof(double), stream);
    }

    curv_main<<<NBLOCKS, 256, 0, stream>>>(phi, acc, use_partials);
    curv_reduce<<<1, 256, 0, stream>>>(acc, NBLOCKS, use_partials, out);
}

// Round 11
// 109.281 us; speedup vs baseline: 1.0240x; 1.0240x over previous
//
#include <hip/hip_runtime.h>

// CurvatureLoss3D — R22: WAVE-PRIVATE LDS staging, ZERO barriers.
// R21 verdict: launch_bounds(256,8) refused (VGPR stuck 68) -> 8-wave tier
// unreachable; occupancy lever exhausted (5 experiments, no movement).
// Remaining theory: the 2 s_barriers/phase enforce lockstep -> all 4 waves
// burst loads together and stall together; wave drift (what makes TLP hide
// latency) is forbidden. Round-0's no-barrier register kernel is the other
// ~40us optimum (drift but 6 redundant VMEM/thread/phase + vmcnt(0) drains).
// R22 = both good halves: per-wave 10-row LDS regions (8 output rows + 2
// halo; no cross-wave reads) -> barriers deleted; per-wave counted-vmcnt
// ladder (R19's, verified) with lgkmcnt(0) merged in so a wave's ds_reads
// retire before it overwrites its own buffer. Halo rows staged 2x
// (40 vs 34 rows: FETCH +18%, irrelevant at 18% BW). LDS 25.6KB.
// Grid/bounds = R19 exactly (720, CZ=19, (256,3)): variables isolated to
// {barriers, staging ownership}. Clamps identical -> bit-identical output.

typedef float v2f __attribute__((ext_vector_type(2)));

constexpr int DIM  = 192;
constexpr int ODIM = 190;
constexpr int TX = 32, TY = 32, CZ = 19;
constexpr int NTX = 6, NTY = 6, NTZ = 10;     // 10*19 = 190 exactly
constexpr int PLANE = DIM * DIM;
constexpr int NBLOCKS = 2 * NTZ * NTY * NTX;  // 720

constexpr int WROWS = 10;                     // rows per wave region (8 out + 2 halo)
constexpr int LROW  = 40;                     // floats per LDS row
constexpr int WPL   = WROWS * LROW;           // 400 floats = 1600 B / wave / plane

struct Slice {
    v2f   q[3][4];          // rows y..y+2; q[dy][k] = (r[k], r[k+2])
    float xmn[4], xmx[4];   // per-voxel-window (3 rows x 3 cols) min/max, this plane
};

#define GLDS(srcp, dstp)                                                   \
    __builtin_amdgcn_global_load_lds(                                      \
        (const __attribute__((address_space(1))) void*)(srcp),             \
        (__attribute__((address_space(3))) void*)(dstp), 16, 0, 0)

// per-wave wait: drain this wave's vmem to N outstanding AND all its LDS
// reads (so the following STAGE may overwrite the buffer it just unpacked)
#define WVMLG(n) asm volatile("s_waitcnt vmcnt(" #n ") lgkmcnt(0)" ::: "memory")

__global__ __launch_bounds__(256, 3) void curv_main(const float* __restrict__ phi,
                                                    double* __restrict__ acc,
                                                    int use_partials) {
    __shared__ float lds[4 * 4 * WPL];        // 4 buffers x 4 waves x 400 = 25600 B

    int bx = blockIdx.x;
    const int tx = bx % NTX; bx /= NTX;
    const int ty = bx % NTY; bx /= NTY;
    const int tz = bx % NTZ; bx /= NTZ;
    const int n  = bx;

    const int xbase = tx * TX, ybase = ty * TY, zbase = tz * CZ;
    const int tid = threadIdx.x;
    const int lane = tid & 63, wave = tid >> 6;
    const int row = tid >> 3;          // output y within tile (0..31)
    const int x0  = (lane & 7) * 4;    // output x within tile (0..28)
    const float* pn  = phi + (long long)n * DIM * PLANE;
    const float* pzb = pn + (long long)zbase * PLANE;   // zbase+g <= 171+20=191: ok

    // ---- per-wave staging map: 100 chunks = 10 rows x 10 float4-chunks ----
    const int chA = lane;                        // chunks 0..63
    const int chB = 64 + lane;                   // chunks 64..99 (lanes 0..35)
    const bool bAct = lane < 36;                 // uniform: 2 vmem/STAGE per wave
    int rA = ybase + wave * 8 + chA / 10; if (rA > DIM - 1) rA = DIM - 1;
    int cA = xbase + (chA % 10) * 4;      if (cA > DIM - 4) cA = DIM - 4;
    const int offA = rA * DIM + cA;
    int rB = ybase + wave * 8 + chB / 10; if (rB > DIM - 1) rB = DIM - 1;
    int cB = xbase + (chB % 10) * 4;      if (cB > DIM - 4) cB = DIM - 4;
    const int offB = rB * DIM + cB;

#define STAGE(g, bi) do {                                                  \
    const float* b_ = pzb + (g) * PLANE;                                   \
    float* w_ = &lds[((bi) * 4 + wave) * WPL];                             \
    GLDS(b_ + offA, w_ + chA * 4);                                         \
    if (bAct) GLDS(b_ + offB, w_ + chB * 4);                               \
} while (0)

    // ---- consumer-side offsets (clamps baked into LDS content) ----
    int lro[3];
#pragma unroll
    for (int dy = 0; dy < 3; ++dy) lro[dy] = ((lane >> 3) + dy) * LROW;
    int c2r = x0 + 4;
    if (xbase + c2r > DIM - 2) c2r = DIM - 2 - xbase;   // last-tile col clamp

#define UNPACKL(S, bi) do {                                                \
    const float* lb_ = &lds[((bi) * 4 + wave) * WPL];                      \
    float mn6[6], mx6[6];                                                  \
    _Pragma("unroll")                                                      \
    for (int dy = 0; dy < 3; ++dy) {                                       \
        const float4 a = *(const float4*)(lb_ + lro[dy] + x0);             \
        const float2 b = *(const float2*)(lb_ + lro[dy] + c2r);            \
        (S).q[dy][0] = (v2f){a.x, a.z};                                    \
        (S).q[dy][1] = (v2f){a.y, a.w};                                    \
        (S).q[dy][2] = (v2f){a.z, b.x};                                    \
        (S).q[dy][3] = (v2f){a.w, b.y};                                    \
        if (dy == 0) {                                                     \
            mn6[0] = a.x; mn6[1] = a.y; mn6[2] = a.z;                      \
            mn6[3] = a.w; mn6[4] = b.x; mn6[5] = b.y;                      \
            mx6[0] = a.x; mx6[1] = a.y; mx6[2] = a.z;                      \
            mx6[3] = a.w; mx6[4] = b.x; mx6[5] = b.y;                      \
        } else {                                                           \
            mn6[0] = fminf(mn6[0], a.x); mx6[0] = fmaxf(mx6[0], a.x);      \
            mn6[1] = fminf(mn6[1], a.y); mx6[1] = fmaxf(mx6[1], a.y);      \
            mn6[2] = fminf(mn6[2], a.z); mx6[2] = fmaxf(mx6[2], a.z);      \
            mn6[3] = fminf(mn6[3], a.w); mx6[3] = fmaxf(mx6[3], a.w);      \
            mn6[4] = fminf(mn6[4], b.x); mx6[4] = fmaxf(mx6[4], b.x);      \
            mn6[5] = fminf(mn6[5], b.y); mx6[5] = fmaxf(mx6[5], b.y);      \
        }                                                                  \
    }                                                                      \
    _Pragma("unroll")                                                      \
    for (int j = 0; j < 4; ++j) {                                          \
        (S).xmn[j] = fminf(fminf(mn6[j], mn6[j + 1]), mn6[j + 2]);         \
        (S).xmx[j] = fmaxf(fmaxf(mx6[j], mx6[j + 1]), mx6[j + 2]);         \
    } } while (0)

    float fsp = 0.0f, fsc = 0.0f;
    const float EPSF = 1e-8f;
    const float EPS4 = 4e-8f;           // 4*eps (exact: eps scaled by 2^2)
    const int oy = ybase + row;

    bool vmask[4];
#pragma unroll
    for (int j = 0; j < 4; ++j)
        vmask[j] = (oy < ODIM) && (xbase + x0 + j < ODIM);

    auto compute = [&](const Slice& s0, const Slice& s1, const Slice& s2) {
        float wmn[4], wmx[4];
#pragma unroll
        for (int j = 0; j < 4; ++j) {
            wmn[j] = fminf(fminf(s0.xmn[j], s1.xmn[j]), s2.xmn[j]);
            wmx[j] = fmaxf(fmaxf(s0.xmx[j], s1.xmx[j]), s2.xmx[j]);
        }

#pragma unroll
        for (int p = 0; p < 2; ++p) {
            // raw differences: G = 2g, M = 4h_mixed (constants folded, exact)
            v2f Gx = s2.q[1][p + 1] - s0.q[1][p + 1];
            v2f Gy = s1.q[2][p + 1] - s1.q[0][p + 1];
            v2f Gz = s1.q[1][p + 2] - s1.q[1][p];

            v2f c2v = 2.0f * s1.q[1][p + 1];
            v2f hxx = s0.q[1][p + 1] - c2v + s2.q[1][p + 1];
            v2f hyy = s1.q[0][p + 1] - c2v + s1.q[2][p + 1];
            v2f hzz = s1.q[1][p] - c2v + s1.q[1][p + 2];

            v2f Mxy = s0.q[0][p + 1] - s0.q[2][p + 1]
                    - s2.q[0][p + 1] + s2.q[2][p + 1];
            v2f Mxz = s0.q[1][p] - s0.q[1][p + 2]
                    - s2.q[1][p] + s2.q[1][p + 2];
            v2f Myz = s1.q[0][p] - s1.q[0][p + 2]
                    - s1.q[2][p] + s1.q[2][p + 2];

            v2f Gx2 = Gx * Gx, Gy2 = Gy * Gy, Gz2 = Gz * Gz;
            v2f mag2G = Gx2 + Gy2 + Gz2 + EPS4;      // = 4*(mag2)

            v2f r = (v2f){ __builtin_amdgcn_rsqf(mag2G.x),
                           __builtin_amdgcn_rsqf(mag2G.y) };   // = inv1/2 exactly
            v2f r3 = r * r * r;                       // = inv3/8
            v2f twor3 = r3 + r3;                      // = inv3/4

            v2f crossG = Gx * Gy * Mxy + Gx * Gz * Mxz + Gy * Gz * Myz; // 16*cross

            v2f num1 = Gx2 * (hyy + hzz) + Gy2 * (hxx + hzz) +
                       Gz2 * (hxx + hyy) - 0.5f * crossG;      // 4*num_orig
            v2f mean_c = num1 * twor3;                // bit-exact vs original
            v2f lap   = (hxx + hyy + hzz) * (r + r);
            v2f num2  = Gx2 * hxx + Gy2 * hyy + Gz2 * hzz + 0.5f * crossG;
            v2f quad  = num2 * twor3;
            v2f gauss = lap - quad;

            v2f disc = mean_c * mean_c - gauss;
            v2f sq = (v2f){ sqrtf(fabsf(disc.x) + EPSF),
                            sqrtf(fabsf(disc.y) + EPSF) };
            v2f k1 = mean_c + sq;
            v2f t  = 2.0f * k1;                       // k1/(0.5+1e-8) == 2*k1
            v2f pen2 = t * t - 1.0f;

#pragma unroll
            for (int e = 0; e < 2; ++e) {
                const int j = p + 2 * e;
                float pen = fmaxf(e ? pen2.y : pen2.x, 0.0f);
                if (vmask[j] && (wmn[j] * wmx[j] < 0.0f)) {
                    fsp += pen;
                    fsc += 1.0f;
                }
            }
        }
    };

    Slice s0, s1, s2;

    // ---- prologue (per-wave, self-paced): planes 0..3 staged ----
    STAGE(0, 0); STAGE(1, 1); STAGE(2, 2); STAGE(3, 3);   // 8 vmem out (this wave)
    WVMLG(6);                   // plane 0 landed (this wave's region)
    UNPACKL(s0, 0);
    WVMLG(4);                   // plane 1 landed; s0 reads retired
    STAGE(4, 0);                // out: {2,3,4} = 6
    UNPACKL(s1, 1);
    WVMLG(4);                   // plane 2 landed; s1 reads retired
    STAGE(5, 1);                // out: {3,4,5} = 6
    // invariant at phase z: this wave's buf[(z+2)%4] ready; 3 planes in flight.

    UNPACKL(s2, 2); compute(s0, s1, s2); WVMLG(4); STAGE(6, 2);   // z=0
    UNPACKL(s0, 3); compute(s1, s2, s0); WVMLG(4); STAGE(7, 3);   // z=1
    UNPACKL(s1, 0); compute(s2, s0, s1); WVMLG(4); STAGE(8, 0);   // z=2
    UNPACKL(s2, 1); compute(s0, s1, s2); WVMLG(4); STAGE(9, 1);   // z=3
    UNPACKL(s0, 2); compute(s1, s2, s0); WVMLG(4); STAGE(10, 2);  // z=4
    UNPACKL(s1, 3); compute(s2, s0, s1); WVMLG(4); STAGE(11, 3);  // z=5
    UNPACKL(s2, 0); compute(s0, s1, s2); WVMLG(4); STAGE(12, 0);  // z=6
    UNPACKL(s0, 1); compute(s1, s2, s0); WVMLG(4); STAGE(13, 1);  // z=7
    UNPACKL(s1, 2); compute(s2, s0, s1); WVMLG(4); STAGE(14, 2);  // z=8
    UNPACKL(s2, 3); compute(s0, s1, s2); WVMLG(4); STAGE(15, 3);  // z=9
    UNPACKL(s0, 0); compute(s1, s2, s0); WVMLG(4); STAGE(16, 0);  // z=10
    UNPACKL(s1, 1); compute(s2, s0, s1); WVMLG(4); STAGE(17, 1);  // z=11
    UNPACKL(s2, 2); compute(s0, s1, s2); WVMLG(4); STAGE(18, 2);  // z=12
    UNPACKL(s0, 3); compute(s1, s2, s0); WVMLG(4); STAGE(19, 3);  // z=13
    UNPACKL(s1, 0); compute(s2, s0, s1); WVMLG(4); STAGE(20, 0);  // z=14
    UNPACKL(s2, 1); compute(s0, s1, s2); WVMLG(4);                // z=15
    UNPACKL(s0, 2); compute(s1, s2, s0); WVMLG(2);                // z=16
    UNPACKL(s1, 3); compute(s2, s0, s1); WVMLG(0);                // z=17
    UNPACKL(s2, 0); compute(s0, s1, s2);                          // z=18

    // ---- reduction (double from here) ----
    double sp = (double)fsp, sc = (double)fsc;
#pragma unroll
    for (int off = 32; off > 0; off >>= 1) {
        sp += __shfl_down(sp, off, 64);
        sc += __shfl_down(sc, off, 64);
    }

    __shared__ double lsp[4], lsc[4];
    if (lane == 0) { lsp[wave] = sp; lsc[wave] = sc; }
    __syncthreads();
    if (tid == 0) {
        double tp = lsp[0] + lsp[1] + lsp[2] + lsp[3];
        double tc = lsc[0] + lsc[1] + lsc[2] + lsc[3];
        if (use_partials) {
            acc[2 * blockIdx.x]     = tp;
            acc[2 * blockIdx.x + 1] = tc;
        } else {
            atomicAdd(&acc[0], tp);
            atomicAdd(&acc[1], tc);
        }
    }
}

__global__ __launch_bounds__(256) void curv_reduce(const double* __restrict__ part,
                                                   int nblocks, int use_partials,
                                                   float* __restrict__ out) {
    double sp = 0.0, sc = 0.0;
    if (use_partials) {
        for (int i = threadIdx.x; i < nblocks; i += 256) {
            sp += part[2 * i];
            sc += part[2 * i + 1];
        }
    } else if (threadIdx.x == 0) {
        sp = part[0]; sc = part[1];
    }
#pragma unroll
    for (int off = 32; off > 0; off >>= 1) {
        sp += __shfl_down(sp, off, 64);
        sc += __shfl_down(sc, off, 64);
    }
    __shared__ double lsp[4], lsc[4];
    const int wave = threadIdx.x >> 6, lane = threadIdx.x & 63;
    if (lane == 0) { lsp[wave] = sp; lsc[wave] = sc; }
    __syncthreads();
    if (threadIdx.x == 0) {
        double tp = lsp[0] + lsp[1] + lsp[2] + lsp[3];
        double tc = lsc[0] + lsc[1] + lsc[2] + lsc[3];
        out[0] = (float)(tp / (tc + 1e-8));
    }
}

extern "C" void kernel_launch(void* const* d_in, const int* in_sizes, int n_in,
                              void* d_out, int out_size, void* d_ws, size_t ws_size,
                              hipStream_t stream) {
    const float* phi = (const float*)d_in[0];
    float* out = (float*)d_out;
    double* acc = (double*)d_ws;

    const int use_partials = (ws_size >= (size_t)(2 * NBLOCKS) * sizeof(double)) ? 1 : 0;
    if (!use_partials) {
        hipMemsetAsync(d_ws, 0, 2 * sizeof(double), stream);
    }

    curv_main<<<NBLOCKS, 256, 0, stream>>>(phi, acc, use_partials);
    curv_reduce<<<1, 256, 0, stream>>>(acc, NBLOCKS, use_partials, out);
}